// Round 12
// baseline (291.039 us; speedup 1.0000x reference)
//
#include <hip/hip_runtime.h>
#include <math.h>

#define NB    4
#define T_SEQ 2048
#define CDIM  1024
#define NH    16
#define DH    64
#define NQKV  3072

typedef short bf16x8 __attribute__((ext_vector_type(8)));
typedef float f32x4  __attribute__((ext_vector_type(4)));

#define GLOBAL_AS __attribute__((address_space(1)))
#define LDS_AS    __attribute__((address_space(3)))

__device__ __forceinline__ void async16(const void* g, void* l) {
  __builtin_amdgcn_global_load_lds((const GLOBAL_AS void*)g, (LDS_AS void*)l, 16, 0, 0);
}

__device__ __forceinline__ unsigned short f2bf(float f) {
  unsigned u = __float_as_uint(f);
  unsigned r = u + 0x7FFF + ((u >> 16) & 1);   // RNE
  return (unsigned short)(r >> 16);
}

// swizzled chunk address (in shorts) for unpadded [rows][64] bf16 tiles:
// row stride 64 shorts; chunk c (8 shorts) stored at slot c ^ (row & 7).
// async16-compatible (linear LDS dest + inverse-swizzled global src) and
// fragment b128 reads across 16 rows land 2-way per bank (free).
#define SWZ8(row, c) ((((row) << 3) | ((c) ^ ((row) & 7))) << 3)

// raw barrier / counted waitcnt (asm so vmcnt is NOT drained like __syncthreads)
#define BARRIER()  asm volatile("s_barrier" ::: "memory")
#define VMCNT(n)   asm volatile("s_waitcnt vmcnt(" #n ")" ::: "memory")

// ---------------------------------------------------------------------------
// Fused prep kernel (single launch):
//   blocks [0, 8192)        : x fp32 -> bf16  (float4 groups)
//   blocks [8192, 11264)    : W_qkv [1024][3072] -> bf16 [3072][1024]
//   blocks [11264, 12288)   : W_out [1024][1024] -> bf16 [1024][1024]^T
//   blocks [12288, 12544)   : RoPE cos/sin table (t*32+d) -> (cos,sin)
// All four are independent (disjoint in/out); branch is block-uniform.
// ---------------------------------------------------------------------------
__device__ __forceinline__ void transpose_tile32(
    const float* __restrict__ in, unsigned short* __restrict__ out,
    int K, int N, int bx, int by, float (*tile)[33], int tid) {
  int n0 = bx << 5, k0 = by << 5;
  int r  = tid >> 3;
  int c4 = (tid & 7) << 2;
  float4 v = *(const float4*)&in[(size_t)(k0 + r) * N + n0 + c4];
  tile[r][c4 + 0] = v.x; tile[r][c4 + 1] = v.y;
  tile[r][c4 + 2] = v.z; tile[r][c4 + 3] = v.w;
  __syncthreads();
  ushort4 o;
  o.x = f2bf(tile[c4 + 0][r]); o.y = f2bf(tile[c4 + 1][r]);
  o.z = f2bf(tile[c4 + 2][r]); o.w = f2bf(tile[c4 + 3][r]);
  *(ushort4*)&out[(size_t)(n0 + r) * K + k0 + c4] = o;
}

__global__ __launch_bounds__(256) void prep_fused(
    const float* __restrict__ x, unsigned short* __restrict__ xb,
    const float* __restrict__ W_qkv, unsigned short* __restrict__ wqt,
    const float* __restrict__ W_out, unsigned short* __restrict__ wot,
    float2* __restrict__ rope) {
  __shared__ float tile[32][33];
  int blk = blockIdx.x;
  int tid = threadIdx.x;
  if (blk < 8192) {                       // convert x -> bf16
    int i = blk * 256 + tid;
    float4 v = ((const float4*)x)[i];
    ushort4 o;
    o.x = f2bf(v.x); o.y = f2bf(v.y); o.z = f2bf(v.z); o.w = f2bf(v.w);
    ((ushort4*)xb)[i] = o;
  } else if (blk < 11264) {               // W_qkv transpose (96 x 32 tiles)
    int local = blk - 8192;
    transpose_tile32(W_qkv, wqt, CDIM, NQKV, local % 96, local / 96, tile, tid);
  } else if (blk < 12288) {               // W_out transpose (32 x 32 tiles)
    int local = blk - 11264;
    transpose_tile32(W_out, wot, CDIM, CDIM, local & 31, local >> 5, tile, tid);
  } else {                                // RoPE table
    int i = (blk - 12288) * 256 + tid;    // 65536 = 2048 * 32
    int t = i >> 5, d = i & 31;
    float inv = expf((float)d * -0.28782313662425572f);
    float s, c;
    sincosf((float)t * inv, &s, &c);
    rope[i] = make_float2(c, s);
  }
}

// ---------------------------------------------------------------------------
// gemm_qkv: 128x256 tile, BK=64, 8 waves (2M x 4N), acc[4][4].
// A staged via 3-buffer rolling counted-vmcnt pipeline (LDS 3x16KB = 48KB).
// B-frags loaded DIRECT from global (wqt is 6MB, L2/L3-resident; address
// provably equals the old LDS path's bytes) -- removes half the LDS-read
// traffic, which was the measured bottleneck (128 ds_read_b128 x 8cy =
// 1024cy vs 307cy MFMA issue per block per K-tile -> MfmaUtil capped ~30%).
// VMCNT(2): B loads self-drain (compiler waits before their MFMAs), so at
// region top outstanding = {A(t)?, A(t+1)}; VMCNT(2) forces A(t) landed.
// __launch_bounds__(512, 2): SAME bound as the proven GEMMs -- round 10's
// (512,6) capped the allocator at 40 VGPRs (< the 64-reg accumulator) and
// spilled everything to scratch (FETCH 970MB, 550us).  This retry changes
// ONLY that.  XCD-chunked 1D block id (bijective 768 = 96*8).
// ---------------------------------------------------------------------------
__global__ __launch_bounds__(512, 2) void gemm_qkv_mfma(
    const unsigned short* __restrict__ A, const unsigned short* __restrict__ Bt,
    const float* __restrict__ bias, const float2* __restrict__ rope,
    unsigned short* __restrict__ qb, unsigned short* __restrict__ kb,
    unsigned short* __restrict__ vtb) {
  __shared__ short As[3][128 * 64];            // 48KB; also V-epilogue scratch
  int orig = blockIdx.x;                       // 768 = 96 * 8
  int wg = (orig & 7) * 96 + (orig >> 3);      // bijective XCD chunking
  int m0 = (wg / 12) << 7, n0 = (wg % 12) << 8;
  int tid = threadIdx.x;
  int wave = tid >> 6, lane = tid & 63;
  int wm = wave >> 2, wn = wave & 3;
  int col = lane & 15, quad = lane >> 4;
  int srow = tid >> 3;
  int schunk = (tid & 7) ^ (srow & 7);
  const unsigned short* aSrc = &A[(size_t)(m0 + srow) * CDIM + schunk * 8];
  int d0 = wave * 512;   // lane-linear LDS dest (shorts) per wave-round
  // B row base pointers; per-region k-offset folds into the load immediate
  const unsigned short* bRow[4];
#pragma unroll
  for (int nt = 0; nt < 4; ++nt)
    bRow[nt] = &Bt[(size_t)(n0 + wn * 64 + nt * 16 + col) * CDIM + quad * 8];

  f32x4 acc[4][4];
#pragma unroll
  for (int mt = 0; mt < 4; ++mt)
#pragma unroll
    for (int nt = 0; nt < 4; ++nt) acc[mt][nt] = (f32x4){0.f, 0.f, 0.f, 0.f};

#define STAGE_A(kt, b)                                                        \
  { const unsigned short* sa_ = aSrc + (kt) * 64;                             \
    async16(sa_,         &As[b][d0]);                                         \
    async16(sa_ + 65536, &As[b][d0 + 4096]); }

  STAGE_A(0, 0)
  STAGE_A(1, 1)
#pragma unroll
  for (int t = 0; t < 16; ++t) {
    if (t < 15) { VMCNT(2); } else { VMCNT(0); }
    BARRIER();
    if (t + 2 < 16) STAGE_A(t + 2, (t + 2) % 3)
    const short* A_ = As[t % 3];
#pragma unroll
    for (int ks = 0; ks < 2; ++ks) {
      bf16x8 af[4], bfr[4];
#pragma unroll
      for (int mt = 0; mt < 4; ++mt)
        af[mt] = *(const bf16x8*)&A_[SWZ8(wm * 64 + mt * 16 + col, ks * 4 + quad)];
#pragma unroll
      for (int nt = 0; nt < 4; ++nt)
        bfr[nt] = *(const bf16x8*)&bRow[nt][t * 64 + ks * 32];
      __builtin_amdgcn_s_setprio(1);
#pragma unroll
      for (int mt = 0; mt < 4; ++mt)
#pragma unroll
        for (int nt = 0; nt < 4; ++nt)
          acc[mt][nt] = __builtin_amdgcn_mfma_f32_16x16x32_bf16(
              af[mt], bfr[nt], acc[mt][nt], 0, 0, 0);
      __builtin_amdgcn_s_setprio(0);
    }
  }

  // Epilogues.  `which` is BLOCK-uniform (n0 multiple of 256; q/k/v
  // boundaries at 1024), so the V branch may use barriers.
  int nn = n0 + wn * 64;            // 64-aligned: whole wave is one (which,h)
  int which = nn >> 10;
  int h = (nn >> 6) & 15;
  float bv[4];
#pragma unroll
  for (int nt = 0; nt < 4; ++nt) bv[nt] = bias[nn + nt * 16 + col];
  if (which < 2) {
    unsigned short* dst = (which == 0) ? qb : kb;
#pragma unroll
    for (int mt = 0; mt < 4; ++mt) {
#pragma unroll
      for (int r = 0; r < 4; ++r) {
        int m = m0 + wm * 64 + mt * 16 + quad * 4 + r;
        int bidx = m >> 11, t = m & 2047;
        float x0 = acc[mt][0][r] + bv[0];
        float x1 = acc[mt][1][r] + bv[1];
        float x2 = acc[mt][2][r] + bv[2];
        float x3 = acc[mt][3][r] + bv[3];
        float2 cs0 = rope[(t << 5) + col];
        float2 cs1 = rope[(t << 5) + col + 16];
        size_t ro = (((size_t)bidx * NH + h) * T_SEQ + t) * DH;
        dst[ro + col]      = f2bf(x0 * cs0.x - x2 * cs0.y);
        dst[ro + col + 16] = f2bf(x1 * cs1.x - x3 * cs1.y);
        dst[ro + col + 32] = f2bf(x2 * cs0.x + x0 * cs0.y);
        dst[ro + col + 48] = f2bf(x3 * cs1.x + x1 * cs1.y);
      }
    }
  } else {
    // V: write directly transposed to vt[b,h,d,t] via a wave-private slice
    // of the dead As buffer.  Two passes of 32 d-rows (32x72 shorts =
    // 4.5KB/wave, 36.9KB total <= 48KB).  Barrier: all waves' final As
    // ds_reads were consumed by their pre-barrier MFMAs (compiler lgkmcnt).
    BARRIER();
    short* scratch = (short*)As + wave * 2304;   // 32 x 72 shorts, pad 72
    int mbase = m0 + wm * 64;                    // 64 consecutive t, same bidx
    int bidx = mbase >> 11, t0v = mbase & 2047;
    size_t vbase = ((size_t)(bidx * NH + h) * DH) * T_SEQ;
#pragma unroll
    for (int p = 0; p < 2; ++p) {
#pragma unroll
      for (int half = 0; half < 2; ++half) {
        int nt = p * 2 + half;
#pragma unroll
        for (int mt = 0; mt < 4; ++mt) {
          float y0 = acc[mt][nt][0] + bv[nt];
          float y1 = acc[mt][nt][1] + bv[nt];
          float y2 = acc[mt][nt][2] + bv[nt];
          float y3 = acc[mt][nt][3] + bv[nt];
          unsigned w0, w1;
          asm("v_cvt_pk_bf16_f32 %0, %1, %2" : "=v"(w0) : "v"(y0), "v"(y1));
          asm("v_cvt_pk_bf16_f32 %0, %1, %2" : "=v"(w1) : "v"(y2), "v"(y3));
          // scratch[d_local][t_local]: d_local = half*16+col, t = mt*16+quad*4
          *(uint2*)&scratch[(half * 16 + col) * 72 + mt * 16 + quad * 4] =
              make_uint2(w0, w1);
        }
      }
      // wave-local round trip (compiler orders lgkmcnt; WAR between passes
      // is same-wave same-address, also compiler-ordered)
#pragma unroll
      for (int u = 0; u < 4; ++u) {
        int f = u * 64 + lane;
        int dl = f >> 3, c = f & 7;
        bf16x8 o = *(const bf16x8*)&scratch[dl * 72 + c * 8];
        *(bf16x8*)&vtb[vbase + (size_t)(p * 32 + dl) * T_SEQ + t0v + c * 8] = o;
      }
    }
  }
}

// ---------------------------------------------------------------------------
// gemm_out: 128x256 tile, BK=64, 3-buffer rolling counted-vmcnt pipeline
// (round-8 proven, untouched).  XCD-chunk swizzle (bijective: 256 = 32*8).
// ---------------------------------------------------------------------------
#define STAGE(kt, b)                                                          \
  { const unsigned short* sa_ = aSrc + (kt) * 64;                             \
    const unsigned short* sb_ = bSrc + (kt) * 64;                             \
    async16(sa_,          &As[b][d0]);                                        \
    async16(sa_ + 65536,  &As[b][d0 + 4096]);                                 \
    async16(sb_,          &Bs[b][d0]);                                        \
    async16(sb_ + 65536,  &Bs[b][d0 + 4096]);                                 \
    async16(sb_ + 131072, &Bs[b][d0 + 8192]);                                 \
    async16(sb_ + 196608, &Bs[b][d0 + 12288]); }

__global__ __launch_bounds__(512, 2) void gemm_out_mfma(
    const unsigned short* __restrict__ A, const unsigned short* __restrict__ Bt,
    const float* __restrict__ bias, float* __restrict__ out) {
  __shared__ short As[3][128 * 64];
  __shared__ short Bs[3][256 * 64];
  int orig = blockIdx.x;                       // 256 = 32 * 8
  int wg = (orig & 7) * 32 + (orig >> 3);      // bijective XCD chunking
  int m0 = (wg >> 2) << 7, n0 = (wg & 3) << 8;
  int tid = threadIdx.x;
  int wave = tid >> 6, lane = tid & 63;
  int wm = wave >> 2, wn = wave & 3;
  int col = lane & 15, quad = lane >> 4;
  int srow = tid >> 3;
  int schunk = (tid & 7) ^ (srow & 7);
  const unsigned short* aSrc = &A[(size_t)(m0 + srow) * CDIM + schunk * 8];
  const unsigned short* bSrc = &Bt[(size_t)(n0 + srow) * CDIM + schunk * 8];
  int d0 = wave * 512;
  f32x4 acc[4][4];
#pragma unroll
  for (int mt = 0; mt < 4; ++mt)
#pragma unroll
    for (int nt = 0; nt < 4; ++nt) acc[mt][nt] = (f32x4){0.f, 0.f, 0.f, 0.f};
  STAGE(0, 0)
  STAGE(1, 1)
#pragma unroll
  for (int t = 0; t < 16; ++t) {
    if (t < 15) { VMCNT(6); } else { VMCNT(0); }
    BARRIER();
    if (t + 2 < 16) STAGE(t + 2, (t + 2) % 3)
    const short* A_ = As[t % 3];
    const short* B_ = Bs[t % 3];
#pragma unroll
    for (int ks = 0; ks < 2; ++ks) {
      bf16x8 af[4], bfr[4];
#pragma unroll
      for (int mt = 0; mt < 4; ++mt)
        af[mt] = *(const bf16x8*)&A_[SWZ8(wm * 64 + mt * 16 + col, ks * 4 + quad)];
#pragma unroll
      for (int nt = 0; nt < 4; ++nt)
        bfr[nt] = *(const bf16x8*)&B_[SWZ8(wn * 64 + nt * 16 + col, ks * 4 + quad)];
      __builtin_amdgcn_s_setprio(1);
#pragma unroll
      for (int mt = 0; mt < 4; ++mt)
#pragma unroll
        for (int nt = 0; nt < 4; ++nt)
          acc[mt][nt] = __builtin_amdgcn_mfma_f32_16x16x32_bf16(
              af[mt], bfr[nt], acc[mt][nt], 0, 0, 0);
      __builtin_amdgcn_s_setprio(0);
    }
  }
#pragma unroll
  for (int nt = 0; nt < 4; ++nt) {
    int n = n0 + wn * 64 + nt * 16 + col;
    float bv = bias[n];
#pragma unroll
    for (int mt = 0; mt < 4; ++mt) {
#pragma unroll
      for (int r = 0; r < 4; ++r) {
        int m = m0 + wm * 64 + mt * 16 + quad * 4 + r;
        out[(size_t)m * CDIM + n] = acc[mt][nt][r] + bv;
      }
    }
  }
}

// ---------------------------------------------------------------------------
// Flash attention (round-8 proven version, frozen): bf16 MFMA, swapped-QK^T,
// 2 K-tiles staged per sync round via __syncthreads.  S^T = mfma(A=K, B=Q);
// P via 2 cvt_pk + ds_write_b64 into SWZ8 region; Q in registers; NO running
// max; row-sum l via ones-vector MFMA.  LDS = 48KB -> 3 blocks/CU.
// ---------------------------------------------------------------------------
__global__ __launch_bounds__(256) void attn_mfma(
    const unsigned short* __restrict__ qg, const unsigned short* __restrict__ kg,
    const unsigned short* __restrict__ vtg, unsigned short* __restrict__ yb) {
  __shared__ short Ks[2][64 * 64];
  __shared__ short Vts[2][64 * 64];
  __shared__ short Ps[4][32 * 64];    // per-wave P [q-row][key], SWZ8 chunks
  int tid = threadIdx.x;
  int wave = tid >> 6, lane = tid & 63;
  int col = lane & 15, quad = lane >> 4;
  int bh = blockIdx.x;
  int qblk = 15 - (int)blockIdx.y;    // deepest blocks dispatch first
  int qb0 = qblk << 7;
  size_t base = (size_t)bh * (T_SEQ * DH);

  // Q fragments in registers (B-operand): qreg[nt][kc], q = qb0+wave*32+nt*16+col
  bf16x8 qreg[2][2];
#pragma unroll
  for (int nt = 0; nt < 2; ++nt)
#pragma unroll
    for (int kc = 0; kc < 2; ++kc)
      qreg[nt][kc] = *(const bf16x8*)&qg[base +
          (size_t)(qb0 + wave * 32 + nt * 16 + col) * DH + kc * 32 + quad * 8];

  bf16x8 ones;
#pragma unroll
  for (int j = 0; j < 8; ++j) ones[j] = (short)0x3F80;  // bf16 1.0

  f32x4 oc[2][4], lsum[2];
#pragma unroll
  for (int mq = 0; mq < 2; ++mq) {
    lsum[mq] = (f32x4){0.f, 0.f, 0.f, 0.f};
#pragma unroll
    for (int dt = 0; dt < 4; ++dt) oc[mq][dt] = (f32x4){0.f, 0.f, 0.f, 0.f};
  }

  int qlo = qb0 + wave * 32;          // wave's first q row
  int qhi = qlo + 31;                 // wave's last q row
  int nrounds = qblk + 1;             // 2 K-tiles (128 keys) per round
  for (int rr = 0; rr < nrounds; ++rr) {
    __syncthreads();                  // all waves done reading prev K/Vt
#pragma unroll
    for (int v = 0; v < 2; ++v) {
      int s_ = (rr * 2 + v) << 6;
#pragma unroll
      for (int u = 0; u < 2; ++u) {
        int ff = u * 256 + wave * 64 + lane;
        int row = ff >> 3, cl = ff & 7;
        int cg = cl ^ (row & 7);
        async16(&kg[base + (size_t)(s_ + row) * DH + cg * 8],
                &Ks[v][(u * 256 + wave * 64) * 8]);
        async16(&vtg[base + (size_t)row * T_SEQ + s_ + cg * 8],
                &Vts[v][(u * 256 + wave * 64) * 8]);
      }
    }
    __syncthreads();                  // staging drained (vmcnt before barrier)

#pragma unroll
    for (int v = 0; v < 2; ++v) {
      int kb = rr * 2 + v;
      int s0 = kb << 6;
      if (s0 > qhi) continue;         // register branch only, no barriers here
      const short* K_ = Ks[v];
      const short* V_ = Vts[v];

      // S^T = K Q^T : 64 keys (M, 4 mf tiles) x 32 q (N, 2 nt tiles)
      f32x4 sc[4][2];
#pragma unroll
      for (int mf = 0; mf < 4; ++mf)
#pragma unroll
        for (int nt = 0; nt < 2; ++nt) sc[mf][nt] = (f32x4){0.f, 0.f, 0.f, 0.f};
#pragma unroll
      for (int kc = 0; kc < 2; ++kc) {
#pragma unroll
        for (int mf = 0; mf < 4; ++mf) {
          bf16x8 ak = *(const bf16x8*)&K_[SWZ8(mf * 16 + col, kc * 4 + quad)];
          sc[mf][0] = __builtin_amdgcn_mfma_f32_16x16x32_bf16(ak, qreg[0][kc], sc[mf][0], 0, 0, 0);
          sc[mf][1] = __builtin_amdgcn_mfma_f32_16x16x32_bf16(ak, qreg[1][kc], sc[mf][1], 0, 0, 0);
        }
      }

      // causal mask: masked if key > q.  key = s0+mf*16+quad*4+r, q = qlo+nt*16+col
      if (s0 + 63 > qlo) {
#pragma unroll
        for (int mf = 0; mf < 4; ++mf) {
          int kbase = s0 + mf * 16 + quad * 4;
#pragma unroll
          for (int nt = 0; nt < 2; ++nt) {
            int qq = qlo + nt * 16 + col;
#pragma unroll
            for (int r = 0; r < 4; ++r)
              if (kbase + r > qq) sc[mf][nt][r] = -3.0e38f;
          }
        }
      }

      // P = exp(S): 4 adjacent keys per (mf,nt) -> 2 cvt_pk + 1 ds_write_b64
      // into swizzled P region.  Wave-local round trip, no barrier.
#pragma unroll
      for (int nt = 0; nt < 2; ++nt) {
        int row = nt * 16 + col;
        int rb = row << 6;
        int sw = row & 7;
#pragma unroll
        for (int mf = 0; mf < 4; ++mf) {
          float p0 = __expf(sc[mf][nt][0]);
          float p1 = __expf(sc[mf][nt][1]);
          float p2 = __expf(sc[mf][nt][2]);
          float p3 = __expf(sc[mf][nt][3]);
          unsigned w0, w1;
          asm("v_cvt_pk_bf16_f32 %0, %1, %2" : "=v"(w0) : "v"(p0), "v"(p1));
          asm("v_cvt_pk_bf16_f32 %0, %1, %2" : "=v"(w1) : "v"(p2), "v"(p3));
          int chunk = (mf << 1) | (quad >> 1);  // (mf*16+quad*4)>>3
          int off = rb + (((chunk ^ sw) << 3) | ((quad & 1) << 2));  // shorts
          *(uint2*)&Ps[wave][off] = make_uint2(w0, w1);
        }
      }

      // O += P V ; l += P . 1   (P as A-frag from swizzled region)
#pragma unroll
      for (int kc = 0; kc < 2; ++kc) {
        bf16x8 ap0 = *(const bf16x8*)&Ps[wave][SWZ8(col,      kc * 4 + quad)];
        bf16x8 ap1 = *(const bf16x8*)&Ps[wave][SWZ8(16 + col, kc * 4 + quad)];
        lsum[0] = __builtin_amdgcn_mfma_f32_16x16x32_bf16(ap0, ones, lsum[0], 0, 0, 0);
        lsum[1] = __builtin_amdgcn_mfma_f32_16x16x32_bf16(ap1, ones, lsum[1], 0, 0, 0);
#pragma unroll
        for (int dt = 0; dt < 4; ++dt) {
          bf16x8 vb = *(const bf16x8*)&V_[SWZ8(dt * 16 + col, kc * 4 + quad)];
          oc[0][dt] = __builtin_amdgcn_mfma_f32_16x16x32_bf16(ap0, vb, oc[0][dt], 0, 0, 0);
          oc[1][dt] = __builtin_amdgcn_mfma_f32_16x16x32_bf16(ap1, vb, oc[1][dt], 0, 0, 0);
        }
      }
    }
  }

  // epilogue: y in (B,T,H,D) bf16 == row-major [B*T][C] for GEMM2
  int b = bh >> 4, h = bh & 15;
#pragma unroll
  for (int mq = 0; mq < 2; ++mq)
#pragma unroll
    for (int dt = 0; dt < 4; ++dt) {
      int d = dt * 16 + col;
#pragma unroll
      for (int r = 0; r < 4; ++r) {
        int t = qb0 + wave * 32 + mq * 16 + quad * 4 + r;
        yb[(((size_t)b * T_SEQ + t) * NH + h) * DH + d] =
            f2bf(oc[mq][dt][r] / lsum[mq][r]);
      }
    }
}

// ---------------------------------------------------------------------------
extern "C" void kernel_launch(void* const* d_in, const int* in_sizes, int n_in,
                              void* d_out, int out_size, void* d_ws, size_t ws_size,
                              hipStream_t stream) {
  const float* x     = (const float*)d_in[0];
  const float* W_qkv = (const float*)d_in[1];
  const float* b_qkv = (const float*)d_in[2];
  const float* W_out = (const float*)d_in[3];
  const float* b_out = (const float*)d_in[4];
  float* out = (float*)d_out;

  const size_t per = (size_t)NB * NH * T_SEQ * DH;  // 8,388,608
  unsigned short* xb  = (unsigned short*)d_ws;
  unsigned short* qb  = xb + per;
  unsigned short* kbf = qb + per;
  unsigned short* vbf = kbf + per;      // unused (kept for layout stability)
  unsigned short* vtb = vbf + per;
  unsigned short* yb  = vtb + per;
  unsigned short* wqt = yb + per;
  unsigned short* wot = wqt + (size_t)NQKV * CDIM;
  float2* rope = (float2*)(wot + (size_t)CDIM * CDIM);
  // total: 6*per + 4*CDIM*CDIM shorts + 512KB rope = ~110 MB

  prep_fused<<<12544, 256, 0, stream>>>(x, xb, W_qkv, wqt, W_out, wot, rope);
  gemm_qkv_mfma<<<768, 512, 0, stream>>>(xb, wqt, b_qkv, rope, qb, kbf, vtb);
  attn_mfma<<<dim3(NB * NH, T_SEQ / 128), 256, 0, stream>>>(qb, kbf, vtb, yb);
  gemm_out_mfma<<<256, 512, 0, stream>>>(yb, wot, b_out, out);
}

// Round 14
// 233.196 us; speedup vs baseline: 1.2480x; 1.2480x over previous
//
#include <hip/hip_runtime.h>
#include <math.h>

#define NB    4
#define T_SEQ 2048
#define CDIM  1024
#define NH    16
#define DH    64
#define NQKV  3072

typedef short bf16x8 __attribute__((ext_vector_type(8)));
typedef float f32x4  __attribute__((ext_vector_type(4)));

#define GLOBAL_AS __attribute__((address_space(1)))
#define LDS_AS    __attribute__((address_space(3)))

__device__ __forceinline__ void async16(const void* g, void* l) {
  __builtin_amdgcn_global_load_lds((const GLOBAL_AS void*)g, (LDS_AS void*)l, 16, 0, 0);
}

__device__ __forceinline__ unsigned short f2bf(float f) {
  unsigned u = __float_as_uint(f);
  unsigned r = u + 0x7FFF + ((u >> 16) & 1);   // RNE
  return (unsigned short)(r >> 16);
}

// swizzled chunk address (in shorts) for unpadded [rows][64] bf16 tiles:
// row stride 64 shorts; chunk c (8 shorts) stored at slot c ^ (row & 7).
// async16-compatible (linear LDS dest + inverse-swizzled global src) and
// fragment b128 reads across 16 rows land 2-way per bank (free).
#define SWZ8(row, c) ((((row) << 3) | ((c) ^ ((row) & 7))) << 3)

// raw barrier / counted waitcnt (asm so vmcnt is NOT drained like __syncthreads)
#define BARRIER()  asm volatile("s_barrier" ::: "memory")
#define VMCNT(n)   asm volatile("s_waitcnt vmcnt(" #n ")" ::: "memory")

// ---------------------------------------------------------------------------
// Fused prep kernel (single launch):
//   blocks [0, 8192)        : x fp32 -> bf16  (float4 groups)
//   blocks [8192, 11264)    : W_qkv [1024][3072] -> bf16 [3072][1024]
//   blocks [11264, 12288)   : W_out [1024][1024] -> bf16 [1024][1024]^T
//   blocks [12288, 12544)   : RoPE cos/sin table (t*32+d) -> (cos,sin)
// All four are independent (disjoint in/out); branch is block-uniform.
// ---------------------------------------------------------------------------
__device__ __forceinline__ void transpose_tile32(
    const float* __restrict__ in, unsigned short* __restrict__ out,
    int K, int N, int bx, int by, float (*tile)[33], int tid) {
  int n0 = bx << 5, k0 = by << 5;
  int r  = tid >> 3;
  int c4 = (tid & 7) << 2;
  float4 v = *(const float4*)&in[(size_t)(k0 + r) * N + n0 + c4];
  tile[r][c4 + 0] = v.x; tile[r][c4 + 1] = v.y;
  tile[r][c4 + 2] = v.z; tile[r][c4 + 3] = v.w;
  __syncthreads();
  ushort4 o;
  o.x = f2bf(tile[c4 + 0][r]); o.y = f2bf(tile[c4 + 1][r]);
  o.z = f2bf(tile[c4 + 2][r]); o.w = f2bf(tile[c4 + 3][r]);
  *(ushort4*)&out[(size_t)(n0 + r) * K + k0 + c4] = o;
}

__global__ __launch_bounds__(256) void prep_fused(
    const float* __restrict__ x, unsigned short* __restrict__ xb,
    const float* __restrict__ W_qkv, unsigned short* __restrict__ wqt,
    const float* __restrict__ W_out, unsigned short* __restrict__ wot,
    float2* __restrict__ rope) {
  __shared__ float tile[32][33];
  int blk = blockIdx.x;
  int tid = threadIdx.x;
  if (blk < 8192) {                       // convert x -> bf16
    int i = blk * 256 + tid;
    float4 v = ((const float4*)x)[i];
    ushort4 o;
    o.x = f2bf(v.x); o.y = f2bf(v.y); o.z = f2bf(v.z); o.w = f2bf(v.w);
    ((ushort4*)xb)[i] = o;
  } else if (blk < 11264) {               // W_qkv transpose (96 x 32 tiles)
    int local = blk - 8192;
    transpose_tile32(W_qkv, wqt, CDIM, NQKV, local % 96, local / 96, tile, tid);
  } else if (blk < 12288) {               // W_out transpose (32 x 32 tiles)
    int local = blk - 11264;
    transpose_tile32(W_out, wot, CDIM, CDIM, local & 31, local >> 5, tile, tid);
  } else {                                // RoPE table
    int i = (blk - 12288) * 256 + tid;    // 65536 = 2048 * 32
    int t = i >> 5, d = i & 31;
    float inv = expf((float)d * -0.28782313662425572f);
    float s, c;
    sincosf((float)t * inv, &s, &c);
    rope[i] = make_float2(c, s);
  }
}

// ---------------------------------------------------------------------------
// bf16 MFMA GEMM, 3-buffer rolling counted-vmcnt pipeline (round-6 proven):
// tile BM=128 x BN=256, BK=64, 8 waves (2M x 4N), acc[4][4].  LDS 144KB.
// Region t: vmcnt(6) -> ONE s_barrier -> stage tile t+2 -> compute tile t.
// 1 barrier/K-tile, prefetch depth 2, vmcnt never drained until last tile.
// m0/n0 from XCD-chunked 1D block id (bijective: nwg % 8 == 0).
// NOTE (r12 lesson): vmcnt is IN-ORDER per wave -- never mix on-demand
// global loads with the async staging stream, or the compiler's waits on
// the former force-drain the latter and the prefetch degenerates.
// ---------------------------------------------------------------------------
#define STAGE(kt, b)                                                          \
  { const unsigned short* sa_ = aSrc + (kt) * 64;                             \
    const unsigned short* sb_ = bSrc + (kt) * 64;                             \
    async16(sa_,          &As[b][d0]);                                        \
    async16(sa_ + 65536,  &As[b][d0 + 4096]);                                 \
    async16(sb_,          &Bs[b][d0]);                                        \
    async16(sb_ + 65536,  &Bs[b][d0 + 4096]);                                 \
    async16(sb_ + 131072, &Bs[b][d0 + 8192]);                                 \
    async16(sb_ + 196608, &Bs[b][d0 + 12288]); }

#define GEMM_PIPE(Aptr, Btptr)                                                \
  int tid = threadIdx.x;                                                      \
  int wave = tid >> 6, lane = tid & 63;                                       \
  int wm = wave >> 2, wn = wave & 3;                                          \
  int col = lane & 15, quad = lane >> 4;                                      \
  int srow = tid >> 3;                                                        \
  int schunk = (tid & 7) ^ (srow & 7);                                        \
  const unsigned short* aSrc = &Aptr[(size_t)(m0 + srow) * CDIM + schunk * 8];\
  const unsigned short* bSrc = &Btptr[(size_t)(n0 + srow) * CDIM + schunk * 8];\
  int d0 = wave * 512; /* lane-linear LDS dest (shorts) per wave-round */     \
  f32x4 acc[4][4];                                                            \
  _Pragma("unroll") for (int mt = 0; mt < 4; ++mt)                            \
  _Pragma("unroll") for (int nt = 0; nt < 4; ++nt)                            \
    acc[mt][nt] = (f32x4){0.f, 0.f, 0.f, 0.f};                                \
  STAGE(0, 0)                                                                 \
  STAGE(1, 1)                                                                 \
  _Pragma("unroll")                                                           \
  for (int t = 0; t < 16; ++t) {                                              \
    if (t < 15) { VMCNT(6); } else { VMCNT(0); }                              \
    BARRIER();                                                                \
    if (t + 2 < 16) STAGE(t + 2, (t + 2) % 3)                                 \
    const short* A_ = As[t % 3];                                              \
    const short* B_ = Bs[t % 3];                                              \
    _Pragma("unroll") for (int ks = 0; ks < 2; ++ks) {                        \
      bf16x8 af[4], bfr[4];                                                   \
      _Pragma("unroll") for (int mt = 0; mt < 4; ++mt)                        \
        af[mt] = *(const bf16x8*)&A_[SWZ8(wm * 64 + mt * 16 + col,            \
                                          ks * 4 + quad)];                    \
      _Pragma("unroll") for (int nt = 0; nt < 4; ++nt)                        \
        bfr[nt] = *(const bf16x8*)&B_[SWZ8(wn * 64 + nt * 16 + col,           \
                                           ks * 4 + quad)];                   \
      __builtin_amdgcn_s_setprio(1);                                          \
      _Pragma("unroll") for (int mt = 0; mt < 4; ++mt)                        \
        _Pragma("unroll") for (int nt = 0; nt < 4; ++nt)                      \
          acc[mt][nt] = __builtin_amdgcn_mfma_f32_16x16x32_bf16(              \
              af[mt], bfr[nt], acc[mt][nt], 0, 0, 0);                         \
      __builtin_amdgcn_s_setprio(0);                                          \
    }                                                                         \
  }

// GEMM1 with fused RoPE epilogue (q/k) and fused V-transpose epilogue (v).
// 1D grid of 768 blocks; XCD-chunk swizzle (bijective: 768 = 96*8).
// `which` is BLOCK-uniform (n0 multiple of 256; q/k/v boundaries at 1024),
// so the V branch may use barriers.  V: each wave holds one 64(t)x64(d)
// tile -> transpose through a wave-PRIVATE slice of the dead Bs buffer
// (all waves' Bs ds_reads drained before their final MFMAs, which precede
// the barrier), then coalesced bf16x8 stores to vt[b,h,d,t].
__global__ __launch_bounds__(512, 2) void gemm_qkv_mfma(
    const unsigned short* __restrict__ A, const unsigned short* __restrict__ Bt,
    const float* __restrict__ bias, const float2* __restrict__ rope,
    unsigned short* __restrict__ qb, unsigned short* __restrict__ kb,
    unsigned short* __restrict__ vtb) {
  __shared__ short As[3][128 * 64];
  __shared__ short Bs[3][256 * 64];
  int orig = blockIdx.x;                       // 768 = 96 * 8
  int wg = (orig & 7) * 96 + (orig >> 3);      // bijective XCD chunking
  int m0 = (wg / 12) << 7, n0 = (wg % 12) << 8;
  GEMM_PIPE(A, Bt)
  int nn = n0 + wn * 64;            // 64-aligned: whole wave is one (which,h)
  int which = nn >> 10;
  int h = (nn >> 6) & 15;
  float bv[4];
#pragma unroll
  for (int nt = 0; nt < 4; ++nt) bv[nt] = bias[nn + nt * 16 + col];
  if (which < 2) {
    unsigned short* dst = (which == 0) ? qb : kb;
#pragma unroll
    for (int mt = 0; mt < 4; ++mt) {
#pragma unroll
      for (int r = 0; r < 4; ++r) {
        int m = m0 + wm * 64 + mt * 16 + quad * 4 + r;
        int bidx = m >> 11, t = m & 2047;
        float x0 = acc[mt][0][r] + bv[0];
        float x1 = acc[mt][1][r] + bv[1];
        float x2 = acc[mt][2][r] + bv[2];
        float x3 = acc[mt][3][r] + bv[3];
        float2 cs0 = rope[(t << 5) + col];
        float2 cs1 = rope[(t << 5) + col + 16];
        size_t ro = (((size_t)bidx * NH + h) * T_SEQ + t) * DH;
        dst[ro + col]      = f2bf(x0 * cs0.x - x2 * cs0.y);
        dst[ro + col + 16] = f2bf(x1 * cs1.x - x3 * cs1.y);
        dst[ro + col + 32] = f2bf(x2 * cs0.x + x0 * cs0.y);
        dst[ro + col + 48] = f2bf(x3 * cs1.x + x1 * cs1.y);
      }
    }
  } else {
    // V: write directly transposed to vt[b,h,d,t] via wave-private LDS tile.
    BARRIER();                        // all waves' Bs reads drained (block-uniform branch)
    short* vt_tile = &Bs[0][0] + wave * (64 * 72);   // 4608 shorts/wave, pad 72
#pragma unroll
    for (int nt = 0; nt < 4; ++nt) {
#pragma unroll
      for (int mt = 0; mt < 4; ++mt) {
        float y0 = acc[mt][nt][0] + bv[nt];
        float y1 = acc[mt][nt][1] + bv[nt];
        float y2 = acc[mt][nt][2] + bv[nt];
        float y3 = acc[mt][nt][3] + bv[nt];
        unsigned w0, w1;
        asm("v_cvt_pk_bf16_f32 %0, %1, %2" : "=v"(w0) : "v"(y0), "v"(y1));
        asm("v_cvt_pk_bf16_f32 %0, %1, %2" : "=v"(w1) : "v"(y2), "v"(y3));
        // vt_tile[d][t_local]: d = nt*16+col, t_local = mt*16+quad*4 (+0..3)
        *(uint2*)&vt_tile[(nt * 16 + col) * 72 + mt * 16 + quad * 4] =
            make_uint2(w0, w1);
      }
    }
    // wave-local round trip (same pattern as attn Ps; compiler orders lgkmcnt)
    int mbase = m0 + wm * 64;                    // 64 consecutive t, same bidx
    int bidx = mbase >> 11, t0v = mbase & 2047;
    size_t vbase = ((size_t)(bidx * NH + h) * DH) * T_SEQ;
#pragma unroll
    for (int u = 0; u < 8; ++u) {
      int f = u * 64 + lane;
      int d = f >> 3, c = f & 7;
      bf16x8 o = *(const bf16x8*)&vt_tile[d * 72 + c * 8];
      *(bf16x8*)&vtb[vbase + (size_t)d * T_SEQ + t0v + c * 8] = o;
    }
  }
}

// 1D grid of 256 blocks; XCD-chunk swizzle (bijective: 256 = 32*8).
__global__ __launch_bounds__(512, 2) void gemm_out_mfma(
    const unsigned short* __restrict__ A, const unsigned short* __restrict__ Bt,
    const float* __restrict__ bias, float* __restrict__ out) {
  __shared__ short As[3][128 * 64];
  __shared__ short Bs[3][256 * 64];
  int orig = blockIdx.x;                       // 256 = 32 * 8
  int wg = (orig & 7) * 32 + (orig >> 3);      // bijective XCD chunking
  int m0 = (wg >> 2) << 7, n0 = (wg & 3) << 8;
  GEMM_PIPE(A, Bt)
#pragma unroll
  for (int nt = 0; nt < 4; ++nt) {
    int n = n0 + wn * 64 + nt * 16 + col;
    float bv = bias[n];
#pragma unroll
    for (int mt = 0; mt < 4; ++mt) {
#pragma unroll
      for (int r = 0; r < 4; ++r) {
        int m = m0 + wm * 64 + mt * 16 + quad * 4 + r;
        out[(size_t)m * CDIM + n] = acc[mt][nt][r] + bv;
      }
    }
  }
}

// ---------------------------------------------------------------------------
// Flash attention, bf16 MFMA, swapped-QK^T, 2 K-tiles per sync round
// (round-7 proven).  S^T = mfma(A=K, B=Q); P via 2 cvt_pk + ds_write_b64
// into SWZ8 region; Q in registers; NO running max; row-sum l via
// ones-vector MFMA.  LDS = 48KB -> 3 blocks/CU.  4 waves x 32 q rows.
// ---------------------------------------------------------------------------
__global__ __launch_bounds__(256) void attn_mfma(
    const unsigned short* __restrict__ qg, const unsigned short* __restrict__ kg,
    const unsigned short* __restrict__ vtg, unsigned short* __restrict__ yb) {
  __shared__ short Ks[2][64 * 64];
  __shared__ short Vts[2][64 * 64];
  __shared__ short Ps[4][32 * 64];    // per-wave P [q-row][key], SWZ8 chunks
  int tid = threadIdx.x;
  int wave = tid >> 6, lane = tid & 63;
  int col = lane & 15, quad = lane >> 4;
  int bh = blockIdx.x;
  int qblk = 15 - (int)blockIdx.y;    // deepest blocks dispatch first
  int qb0 = qblk << 7;
  size_t base = (size_t)bh * (T_SEQ * DH);

  // Q fragments in registers (B-operand): qreg[nt][kc], q = qb0+wave*32+nt*16+col
  bf16x8 qreg[2][2];
#pragma unroll
  for (int nt = 0; nt < 2; ++nt)
#pragma unroll
    for (int kc = 0; kc < 2; ++kc)
      qreg[nt][kc] = *(const bf16x8*)&qg[base +
          (size_t)(qb0 + wave * 32 + nt * 16 + col) * DH + kc * 32 + quad * 8];

  bf16x8 ones;
#pragma unroll
  for (int j = 0; j < 8; ++j) ones[j] = (short)0x3F80;  // bf16 1.0

  f32x4 oc[2][4], lsum[2];
#pragma unroll
  for (int mq = 0; mq < 2; ++mq) {
    lsum[mq] = (f32x4){0.f, 0.f, 0.f, 0.f};
#pragma unroll
    for (int dt = 0; dt < 4; ++dt) oc[mq][dt] = (f32x4){0.f, 0.f, 0.f, 0.f};
  }

  int qlo = qb0 + wave * 32;          // wave's first q row
  int qhi = qlo + 31;                 // wave's last q row
  int nrounds = qblk + 1;             // 2 K-tiles (128 keys) per round
  for (int rr = 0; rr < nrounds; ++rr) {
    __syncthreads();                  // all waves done reading prev K/Vt
#pragma unroll
    for (int v = 0; v < 2; ++v) {
      int s_ = (rr * 2 + v) << 6;
#pragma unroll
      for (int u = 0; u < 2; ++u) {
        int ff = u * 256 + wave * 64 + lane;
        int row = ff >> 3, cl = ff & 7;
        int cg = cl ^ (row & 7);
        async16(&kg[base + (size_t)(s_ + row) * DH + cg * 8],
                &Ks[v][(u * 256 + wave * 64) * 8]);
        async16(&vtg[base + (size_t)row * T_SEQ + s_ + cg * 8],
                &Vts[v][(u * 256 + wave * 64) * 8]);
      }
    }
    __syncthreads();                  // staging drained (vmcnt before barrier)

#pragma unroll
    for (int v = 0; v < 2; ++v) {
      int kb = rr * 2 + v;
      int s0 = kb << 6;
      if (s0 > qhi) continue;         // register branch only, no barriers here
      const short* K_ = Ks[v];
      const short* V_ = Vts[v];

      // S^T = K Q^T : 64 keys (M, 4 mf tiles) x 32 q (N, 2 nt tiles)
      f32x4 sc[4][2];
#pragma unroll
      for (int mf = 0; mf < 4; ++mf)
#pragma unroll
        for (int nt = 0; nt < 2; ++nt) sc[mf][nt] = (f32x4){0.f, 0.f, 0.f, 0.f};
#pragma unroll
      for (int kc = 0; kc < 2; ++kc) {
#pragma unroll
        for (int mf = 0; mf < 4; ++mf) {
          bf16x8 ak = *(const bf16x8*)&K_[SWZ8(mf * 16 + col, kc * 4 + quad)];
          sc[mf][0] = __builtin_amdgcn_mfma_f32_16x16x32_bf16(ak, qreg[0][kc], sc[mf][0], 0, 0, 0);
          sc[mf][1] = __builtin_amdgcn_mfma_f32_16x16x32_bf16(ak, qreg[1][kc], sc[mf][1], 0, 0, 0);
        }
      }

      // causal mask: masked if key > q.  key = s0+mf*16+quad*4+r, q = qlo+nt*16+col
      if (s0 + 63 > qlo) {
#pragma unroll
        for (int mf = 0; mf < 4; ++mf) {
          int kbase = s0 + mf * 16 + quad * 4;
#pragma unroll
          for (int nt = 0; nt < 2; ++nt) {
            int qq = qlo + nt * 16 + col;
#pragma unroll
            for (int r = 0; r < 4; ++r)
              if (kbase + r > qq) sc[mf][nt][r] = -3.0e38f;
          }
        }
      }

      // P = exp(S): 4 adjacent keys per (mf,nt) -> 2 cvt_pk + 1 ds_write_b64
      // into swizzled P region.  Wave-local round trip, no barrier.
#pragma unroll
      for (int nt = 0; nt < 2; ++nt) {
        int row = nt * 16 + col;
        int rb = row << 6;
        int sw = row & 7;
#pragma unroll
        for (int mf = 0; mf < 4; ++mf) {
          float p0 = __expf(sc[mf][nt][0]);
          float p1 = __expf(sc[mf][nt][1]);
          float p2 = __expf(sc[mf][nt][2]);
          float p3 = __expf(sc[mf][nt][3]);
          unsigned w0, w1;
          asm("v_cvt_pk_bf16_f32 %0, %1, %2" : "=v"(w0) : "v"(p0), "v"(p1));
          asm("v_cvt_pk_bf16_f32 %0, %1, %2" : "=v"(w1) : "v"(p2), "v"(p3));
          int chunk = (mf << 1) | (quad >> 1);  // (mf*16+quad*4)>>3
          int off = rb + (((chunk ^ sw) << 3) | ((quad & 1) << 2));  // shorts
          *(uint2*)&Ps[wave][off] = make_uint2(w0, w1);
        }
      }

      // O += P V ; l += P . 1   (P as A-frag from swizzled region)
#pragma unroll
      for (int kc = 0; kc < 2; ++kc) {
        bf16x8 ap0 = *(const bf16x8*)&Ps[wave][SWZ8(col,      kc * 4 + quad)];
        bf16x8 ap1 = *(const bf16x8*)&Ps[wave][SWZ8(16 + col, kc * 4 + quad)];
        lsum[0] = __builtin_amdgcn_mfma_f32_16x16x32_bf16(ap0, ones, lsum[0], 0, 0, 0);
        lsum[1] = __builtin_amdgcn_mfma_f32_16x16x32_bf16(ap1, ones, lsum[1], 0, 0, 0);
#pragma unroll
        for (int dt = 0; dt < 4; ++dt) {
          bf16x8 vb = *(const bf16x8*)&V_[SWZ8(dt * 16 + col, kc * 4 + quad)];
          oc[0][dt] = __builtin_amdgcn_mfma_f32_16x16x32_bf16(ap0, vb, oc[0][dt], 0, 0, 0);
          oc[1][dt] = __builtin_amdgcn_mfma_f32_16x16x32_bf16(ap1, vb, oc[1][dt], 0, 0, 0);
        }
      }
    }
  }

  // epilogue: y in (B,T,H,D) bf16 == row-major [B*T][C] for GEMM2
  int b = bh >> 4, h = bh & 15;
#pragma unroll
  for (int mq = 0; mq < 2; ++mq)
#pragma unroll
    for (int dt = 0; dt < 4; ++dt) {
      int d = dt * 16 + col;
#pragma unroll
      for (int r = 0; r < 4; ++r) {
        int t = qb0 + wave * 32 + mq * 16 + quad * 4 + r;
        yb[(((size_t)b * T_SEQ + t) * NH + h) * DH + d] =
            f2bf(oc[mq][dt][r] / lsum[mq][r]);
      }
    }
}

// ---------------------------------------------------------------------------
extern "C" void kernel_launch(void* const* d_in, const int* in_sizes, int n_in,
                              void* d_out, int out_size, void* d_ws, size_t ws_size,
                              hipStream_t stream) {
  const float* x     = (const float*)d_in[0];
  const float* W_qkv = (const float*)d_in[1];
  const float* b_qkv = (const float*)d_in[2];
  const float* W_out = (const float*)d_in[3];
  const float* b_out = (const float*)d_in[4];
  float* out = (float*)d_out;

  const size_t per = (size_t)NB * NH * T_SEQ * DH;  // 8,388,608
  unsigned short* xb  = (unsigned short*)d_ws;
  unsigned short* qb  = xb + per;
  unsigned short* kbf = qb + per;
  unsigned short* vbf = kbf + per;      // unused (kept for layout stability)
  unsigned short* vtb = vbf + per;
  unsigned short* yb  = vtb + per;
  unsigned short* wqt = yb + per;
  unsigned short* wot = wqt + (size_t)NQKV * CDIM;
  float2* rope = (float2*)(wot + (size_t)CDIM * CDIM);
  // total: 6*per + 4*CDIM*CDIM shorts + 512KB rope = ~110 MB

  prep_fused<<<12544, 256, 0, stream>>>(x, xb, W_qkv, wqt, W_out, wot, rope);
  gemm_qkv_mfma<<<768, 512, 0, stream>>>(xb, wqt, b_qkv, rope, qb, kbf, vtb);
  attn_mfma<<<dim3(NB * NH, T_SEQ / 128), 256, 0, stream>>>(qb, kbf, vtb, yb);
  gemm_out_mfma<<<256, 512, 0, stream>>>(yb, wot, b_out, out);
}